// Round 5
// baseline (483.980 us; speedup 1.0000x reference)
//
#include <hip/hip_runtime.h>
#include <hip/hip_bf16.h>

#define T_DIM 32772
#define NGROUP 2048

typedef short short8v __attribute__((ext_vector_type(8)));
typedef float float4v __attribute__((ext_vector_type(4)));
typedef unsigned int uint4v __attribute__((ext_vector_type(4)));

// packed f32x2 -> bf16x2 (RTNE) -> u32; compiler emits v_cvt_pk_bf16_f32
__device__ __forceinline__ unsigned int f2bf2(float a, float b) {
    __hip_bfloat162 h = __float22bfloat162_rn(make_float2(a, b));
    union { __hip_bfloat162 h; unsigned int u; } c; c.h = h;
    return c.u;
}

__device__ __forceinline__ short8v pack8(const float4v u0, const float4v u1) {
    uint4v p;
    p[0] = f2bf2(u0[0], u0[1]);
    p[1] = f2bf2(u0[2], u0[3]);
    p[2] = f2bf2(u1[0], u1[1]);
    p[3] = f2bf2(u1[2], u1[3]);
    return __builtin_bit_cast(short8v, p);
}

// One block per chamfer group g (B*H=2048), 8 waves, occupancy-first (VGPR<=64).
// x = targ obs (n, 256x128): per-wave register A-frags (wave w owns rows 32w..32w+31).
// y = preds obs (m, 256x128): 4 chunks of 64 rows, double-buffered bf16 in LDS.
// Decomposition: zz = x.y ; rowmin tracks min_m(y2-2zz) (x2 added at end);
//                colmin tracks min_n(x2-2zz) (y2 added in final combine).
__global__ __launch_bounds__(512, 8) void chamfer_kernel(
    const float* __restrict__ preds, const float* __restrict__ targ,
    float* __restrict__ ch_out)
{
    __shared__ __align__(16) unsigned short Ys[2][64 * 128]; // 2 x 16 KB bf16
    __shared__ float y2s[256];
    __shared__ float x2s[256];
    __shared__ float redA[8];
    __shared__ float redB[4];
    // colmin [8][256] aliased onto Ys buffer 0 (dead after chunk-2's barrier;
    // chunk 3 computes from buffer 1 only)
    float* colmin_alias = reinterpret_cast<float*>(&Ys[0][0]);

    const int g = blockIdx.x;
    const float* gx = targ  + (size_t)g * T_DIM + 4;
    const float* gy = preds + (size_t)g * T_DIM + 4;

    const int tid  = threadIdx.x;
    const int lane = tid & 63;
    const int w    = tid >> 6;   // wave 0..7
    const int lg   = lane >> 4;  // k-quarter 0..3
    const int lc   = lane & 15;  // row/col within 16-tile

    // staging decomposition: 8 threads per y-row; thread owns 16B chunks pcb, pcb+8
    const int prow = tid >> 3;   // row within chunk 0..63
    const int pcb  = tid & 7;    // chunk pair selector 0..7
    char* Ysb = (char*)Ys;
    const int wslot = ((pcb + prow) & 7) << 4;
    const int woffA = prow * 256 + wslot;
    const int woffB = prow * 256 + 128 + wslot;

    // ---- A fragments to registers + x2 to LDS ----
    short8v a_frag[2][4];
    #pragma unroll
    for (int ti = 0; ti < 2; ++ti) {
        const float* xr = gx + (size_t)(w * 32 + ti * 16 + lc) * 128;
        float ss = 0.f;
        #pragma unroll
        for (int kk = 0; kk < 4; ++kk) {
            const float4v u0 = *reinterpret_cast<const float4v*>(xr + kk * 32 + lg * 8);
            const float4v u1 = *reinterpret_cast<const float4v*>(xr + kk * 32 + lg * 8 + 4);
            ss += u0[0]*u0[0] + u0[1]*u0[1] + u0[2]*u0[2] + u0[3]*u0[3];
            ss += u1[0]*u1[0] + u1[1]*u1[1] + u1[2]*u1[2] + u1[3]*u1[3];
            a_frag[ti][kk] = pack8(u0, u1);
        }
        ss += __shfl_xor(ss, 16);
        ss += __shfl_xor(ss, 32);
        if (lg == 0) x2s[w * 32 + ti * 16 + lc] = ss; // own-wave rows only
    }

    float rowmin[2][4];
    #pragma unroll
    for (int ti = 0; ti < 2; ++ti)
        #pragma unroll
        for (int r = 0; r < 4; ++r) rowmin[ti][r] = 1e30f;
    float cmin[4];

    // read slots (conflict-free add-rotate, proven in R4)
    const int rs0 = ((lg + lc) & 7) << 4;
    const int rs1 = ((lg + lc + 4) & 7) << 4;
    const int x2byte = (w * 32 + lg * 4) * 4; // + ti*64 bytes

    // ---- 4 chunks: stage -> barrier -> compute (TLP hides staging latency) ----
    #pragma unroll
    for (int c = 0; c < 4; ++c) {
        // stage chunk c into buffer c&1 (safe: all waves finished compute c-2
        // on this buffer before the barrier that preceded compute c-1)
        {
            const float* src = gy + (size_t)(c * 64 + prow) * 128 + pcb * 8;
            const float4v pf0 = *reinterpret_cast<const float4v*>(src);
            const float4v pf1 = *reinterpret_cast<const float4v*>(src + 4);
            const float4v pf2 = *reinterpret_cast<const float4v*>(src + 64);
            const float4v pf3 = *reinterpret_cast<const float4v*>(src + 68);
            float ss = pf0[0]*pf0[0]+pf0[1]*pf0[1]+pf0[2]*pf0[2]+pf0[3]*pf0[3]
                     + pf1[0]*pf1[0]+pf1[1]*pf1[1]+pf1[2]*pf1[2]+pf1[3]*pf1[3]
                     + pf2[0]*pf2[0]+pf2[1]*pf2[1]+pf2[2]*pf2[2]+pf2[3]*pf2[3]
                     + pf3[0]*pf3[0]+pf3[1]*pf3[1]+pf3[2]*pf3[2]+pf3[3]*pf3[3];
            ss += __shfl_xor(ss, 1);
            ss += __shfl_xor(ss, 2);
            ss += __shfl_xor(ss, 4);
            if (pcb == 0) y2s[c * 64 + prow] = ss;
            char* wbuf = Ysb + (c & 1) * 16384;
            *reinterpret_cast<short8v*>(wbuf + woffA) = pack8(pf0, pf1);
            *reinterpret_cast<short8v*>(wbuf + woffB) = pack8(pf2, pf3);
        }
        __syncthreads();

        // compute chunk c from buffer c&1
        char* buf = Ysb + (c & 1) * 16384;
        #pragma unroll
        for (int tjl = 0; tjl < 4; ++tjl) {
            const int tj = c * 4 + tjl;
            const int rbyte = (tjl * 16 + lc) * 256;
            const float y2c = y2s[tj * 16 + lc];

            // paired B reads + interleaved dual-ti MFMA (caps live b-regs at 8)
            float4v acc0 = {0.f, 0.f, 0.f, 0.f};
            float4v acc1 = {0.f, 0.f, 0.f, 0.f};
            {
                short8v b0 = *reinterpret_cast<const short8v*>(buf + rbyte + rs0);
                short8v b1 = *reinterpret_cast<const short8v*>(buf + rbyte + rs1);
                acc0 = __builtin_amdgcn_mfma_f32_16x16x32_bf16(a_frag[0][0], b0, acc0, 0, 0, 0);
                acc1 = __builtin_amdgcn_mfma_f32_16x16x32_bf16(a_frag[1][0], b0, acc1, 0, 0, 0);
                acc0 = __builtin_amdgcn_mfma_f32_16x16x32_bf16(a_frag[0][1], b1, acc0, 0, 0, 0);
                acc1 = __builtin_amdgcn_mfma_f32_16x16x32_bf16(a_frag[1][1], b1, acc1, 0, 0, 0);
                b0 = *reinterpret_cast<const short8v*>(buf + rbyte + 128 + rs0);
                b1 = *reinterpret_cast<const short8v*>(buf + rbyte + 128 + rs1);
                acc0 = __builtin_amdgcn_mfma_f32_16x16x32_bf16(a_frag[0][2], b0, acc0, 0, 0, 0);
                acc1 = __builtin_amdgcn_mfma_f32_16x16x32_bf16(a_frag[1][2], b0, acc1, 0, 0, 0);
                acc0 = __builtin_amdgcn_mfma_f32_16x16x32_bf16(a_frag[0][3], b1, acc0, 0, 0, 0);
                acc1 = __builtin_amdgcn_mfma_f32_16x16x32_bf16(a_frag[1][3], b1, acc1, 0, 0, 0);
            }

            float cminv = 1e30f;
            {
                const float4v x2v = *reinterpret_cast<const float4v*>((char*)x2s + x2byte);
                #pragma unroll
                for (int r = 0; r < 4; ++r) {
                    const float t = -2.0f * acc0[r];
                    rowmin[0][r] = fminf(rowmin[0][r], y2c + t);
                    cminv = fminf(cminv, x2v[r] + t);
                }
            }
            {
                const float4v x2v = *reinterpret_cast<const float4v*>((char*)x2s + x2byte + 64);
                #pragma unroll
                for (int r = 0; r < 4; ++r) {
                    const float t = -2.0f * acc1[r];
                    rowmin[1][r] = fminf(rowmin[1][r], y2c + t);
                    cminv = fminf(cminv, x2v[r] + t);
                }
            }
            // min over the wave's 32 rows (combine 4 lane groups), broadcast
            cminv = fminf(cminv, __shfl_xor(cminv, 16));
            cminv = fminf(cminv, __shfl_xor(cminv, 32));
            if (lg == tjl) cmin[c] = cminv; // col = c*64 + lane
        }
    }

    // ---- per-wave col-mins -> aliased LDS (buffer 0 is dead now) ----
    #pragma unroll
    for (int s = 0; s < 4; ++s)
        colmin_alias[w * 256 + s * 64 + lane] = cmin[s];

    // ---- loss2: row-mins; add x2[row] at the end ----
    float s2 = 0.f;
    #pragma unroll
    for (int ti = 0; ti < 2; ++ti) {
        const float4v x2v = *reinterpret_cast<const float4v*>((char*)x2s + x2byte + ti * 64);
        #pragma unroll
        for (int r = 0; r < 4; ++r) {
            float v = rowmin[ti][r];
            v = fminf(v, __shfl_xor(v, 1));
            v = fminf(v, __shfl_xor(v, 2));
            v = fminf(v, __shfl_xor(v, 4));
            v = fminf(v, __shfl_xor(v, 8));
            s2 += x2v[r] + v;
        }
    }
    s2 += __shfl_xor(s2, 16);
    s2 += __shfl_xor(s2, 32);
    if (lane == 0) redA[w] = s2;
    __syncthreads();

    // ---- loss1: min over 8 waves per col, add y2[col], sum over 256 cols ----
    if (tid < 256) {
        float m = colmin_alias[tid];
        #pragma unroll
        for (int ww = 1; ww < 8; ++ww) m = fminf(m, colmin_alias[ww * 256 + tid]);
        m += y2s[tid];
        #pragma unroll
        for (int s = 1; s < 64; s <<= 1) m += __shfl_xor(m, s);
        if (lane == 0) redB[w] = m;
    }
    __syncthreads();
    if (tid == 0) {
        const float l1 = redB[0] + redB[1] + redB[2] + redB[3];
        float l2 = 0.f;
        #pragma unroll
        for (int ww = 0; ww < 8; ++ww) l2 += redA[ww];
        ch_out[g] = l1 + l2;
    }
}

// Action loss + final reduction -> out[0], out[1]
__global__ __launch_bounds__(256) void final_kernel(
    const float* __restrict__ preds, const float* __restrict__ targ,
    const float* __restrict__ ch, float* __restrict__ out)
{
    __shared__ float rsw[4], rsa[4], rsc[4];
    const int tid = threadIdx.x;
    const int lane = tid & 63, w = tid >> 6;
    float sw = 0.f, sa0 = 0.f, sc = 0.f;
    for (int p = tid; p < NGROUP; p += 256) {
        const float* pp = preds + (size_t)p * T_DIM;
        const float* tt = targ  + (size_t)p * T_DIM;
        float al = 0.f;
        #pragma unroll
        for (int d = 0; d < 4; ++d) { const float df = pp[d] - tt[d]; al += df * df; }
        al *= 0.25f;
        if ((p & 31) == 0) { sw += 10.f * al; sa0 += al; }
        else               { sw += al; }
        sc += ch[p];
    }
    #pragma unroll
    for (int s = 1; s < 64; s <<= 1) {
        sw  += __shfl_xor(sw, s);
        sa0 += __shfl_xor(sa0, s);
        sc  += __shfl_xor(sc, s);
    }
    if (lane == 0) { rsw[w] = sw; rsa[w] = sa0; rsc[w] = sc; }
    __syncthreads();
    if (tid == 0) {
        float tsw = 0.f, tsa = 0.f, tsc = 0.f;
        #pragma unroll
        for (int i = 0; i < 4; ++i) { tsw += rsw[i]; tsa += rsa[i]; tsc += rsc[i]; }
        out[0] = tsw / 2048.f + tsc / 2048.f;
        out[1] = tsa / 64.f;
    }
}

extern "C" void kernel_launch(void* const* d_in, const int* in_sizes, int n_in,
                              void* d_out, int out_size, void* d_ws, size_t ws_size,
                              hipStream_t stream) {
    const float* preds = (const float*)d_in[0];
    const float* targ  = (const float*)d_in[1];
    float* out = (float*)d_out;
    float* ch  = (float*)d_ws; // 2048 floats of per-group chamfer
    chamfer_kernel<<<NGROUP, 512, 0, stream>>>(preds, targ, ch);
    final_kernel<<<1, 256, 0, stream>>>(preds, targ, ch, out);
}

// Round 6
// 187.475 us; speedup vs baseline: 2.5816x; 2.5816x over previous
//
#include <hip/hip_runtime.h>
#include <hip/hip_bf16.h>

#define T_DIM 32772
#define NGROUP 2048

typedef short short8v __attribute__((ext_vector_type(8)));
typedef float float4v __attribute__((ext_vector_type(4)));
typedef unsigned int uint4v __attribute__((ext_vector_type(4)));

// packed f32x2 -> bf16x2 (RTNE) -> u32; compiler emits v_cvt_pk_bf16_f32
__device__ __forceinline__ unsigned int f2bf2(float a, float b) {
    __hip_bfloat162 h = __float22bfloat162_rn(make_float2(a, b));
    union { __hip_bfloat162 h; unsigned int u; } c; c.h = h;
    return c.u;
}

__device__ __forceinline__ short8v pack8(const float4v u0, const float4v u1) {
    uint4v p;
    p[0] = f2bf2(u0[0], u0[1]);
    p[1] = f2bf2(u0[2], u0[3]);
    p[2] = f2bf2(u1[0], u1[1]);
    p[3] = f2bf2(u1[2], u1[3]);
    return __builtin_bit_cast(short8v, p);
}

// async global->LDS, 16B per lane; LDS dest = wave-uniform base + lane*16
__device__ __forceinline__ void dma16(const void* g, void* l) {
    __builtin_amdgcn_global_load_lds(
        (const __attribute__((address_space(1))) unsigned int*)g,
        (__attribute__((address_space(3))) unsigned int*)l, 16, 0, 0);
}

// One block per chamfer group g (B*H=2048), 8 waves.
// x = targ obs (n, 256x128): per-wave register A-frags (wave w owns rows 32w..32w+31).
// y = preds obs (m, 256x128): 4 chunks of 64 rows, f32 double-buffered in LDS via
//     global_load_lds (pre-swizzled source), counted-vmcnt pipeline (4,4,4,0).
// Waves cvt f32->bf16 at B-read time and derive y2 from the same registers.
// P = x2[n] + y2[m] - 2*x.y ; loss1 = sum_m min_n P ; loss2 = sum_n min_m P
__global__ __launch_bounds__(512) void chamfer_kernel(
    const float* __restrict__ preds, const float* __restrict__ targ,
    float* __restrict__ ch_out)
{
    __shared__ __align__(16) float YsF[2][8192]; // 2 x 32 KB f32 y-chunks (swizzled)
    __shared__ float x2s[256];
    __shared__ float redA[8];
    __shared__ float redB[4];
    // colmin [8][256] aliased onto YsF[0] (last read of buf 0 is chunk 2)
    float* colmin_alias = &YsF[0][0];

    const int g = blockIdx.x;
    const float* gx = targ  + (size_t)g * T_DIM + 4;
    const float* gy = preds + (size_t)g * T_DIM + 4;
    const char* gyb = (const char*)gy;

    const int tid  = threadIdx.x;
    const int lane = tid & 63;
    const int w    = tid >> 6;   // wave 0..7
    const int lg   = lane >> 4;  // k-quarter 0..3
    const int lc   = lane & 15;  // row/col within 16-tile

    // DMA source offsets (within 32KB chunk): dest ld = seg*1024 + lane*16 (linear),
    // source = ld ^ ((row&7)<<4), row = ld>>9  (XOR permutes within 128B -> coalesced)
    int dma_src[4];
    #pragma unroll
    for (int i = 0; i < 4; ++i) {
        const int ldlin = (w * 4 + i) * 1024 + lane * 16;
        const int row = ldlin >> 9;
        dma_src[i] = ldlin ^ ((row & 7) << 4);
    }

    auto issue_chunk = [&](int c) {
        const char* srcb = gyb + c * 32768;
        char* dstb = (char*)&YsF[c & 1][0];
        #pragma unroll
        for (int i = 0; i < 4; ++i)
            dma16(srcb + dma_src[i], dstb + (w * 4 + i) * 1024);
    };

    // ---- issue y chunks 0,1 immediately (ride out the whole x-phase) ----
    issue_chunk(0);
    issue_chunk(1);
    __builtin_amdgcn_sched_barrier(0);

    // ---- A fragments to registers + x2 to LDS (own-wave rows; no barrier) ----
    short8v a_frag[2][4];
    #pragma unroll
    for (int ti = 0; ti < 2; ++ti) {
        const float* xr = gx + (size_t)(w * 32 + ti * 16 + lc) * 128;
        float ss = 0.f;
        #pragma unroll
        for (int kk = 0; kk < 4; ++kk) {
            const float4v u0 = *reinterpret_cast<const float4v*>(xr + kk * 32 + lg * 8);
            const float4v u1 = *reinterpret_cast<const float4v*>(xr + kk * 32 + lg * 8 + 4);
            ss += u0[0]*u0[0] + u0[1]*u0[1] + u0[2]*u0[2] + u0[3]*u0[3];
            ss += u1[0]*u1[0] + u1[1]*u1[1] + u1[2]*u1[2] + u1[3]*u1[3];
            a_frag[ti][kk] = pack8(u0, u1);
        }
        ss += __shfl_xor(ss, 16);
        ss += __shfl_xor(ss, 32);
        if (lg == 0) x2s[w * 32 + ti * 16 + lc] = ss; // read only by own wave
    }

    float rowmin[2][4];
    #pragma unroll
    for (int ti = 0; ti < 2; ++ti)
        #pragma unroll
        for (int r = 0; r < 4; ++r) rowmin[ti][r] = 1e30f;
    float cmin[4];

    const int x2byte = (w * 32 + lg * 4) * 4; // + ti*64 bytes
    const int bm = (lc & 7) << 4;             // read-side swizzle mask

    // ---- 4 chunks, counted-vmcnt pipeline; vmcnt waits: 4,4,4,0 ----
    #pragma unroll
    for (int c = 0; c < 4; ++c) {
        if (c < 3) asm volatile("s_waitcnt vmcnt(4)" ::: "memory");
        else       asm volatile("s_waitcnt vmcnt(0)" ::: "memory");
        __builtin_amdgcn_s_barrier();          // all waves' chunk-c DMA landed
        __builtin_amdgcn_sched_barrier(0);

        const char* buf = (const char*)&YsF[c & 1][0];
        #pragma unroll
        for (int tjl = 0; tjl < 4; ++tjl) {
            const int rb = (tjl * 16 + lc) * 512; // f32 row stride 512B
            float4v v[8];
            #pragma unroll
            for (int kk = 0; kk < 4; ++kk) {
                const int a0 = (rb + kk * 128 + lg * 32) ^ bm;
                v[2*kk]   = *reinterpret_cast<const float4v*>(buf + a0);
                v[2*kk+1] = *reinterpret_cast<const float4v*>(buf + (a0 ^ 16));
            }
            // y2 of this lane's col (partial over lg quarters, combined via shfl)
            float yq = 0.f;
            #pragma unroll
            for (int q = 0; q < 8; ++q)
                yq += v[q][0]*v[q][0] + v[q][1]*v[q][1] + v[q][2]*v[q][2] + v[q][3]*v[q][3];
            yq += __shfl_xor(yq, 16);
            yq += __shfl_xor(yq, 32);

            float4v acc0 = {0.f, 0.f, 0.f, 0.f};
            float4v acc1 = {0.f, 0.f, 0.f, 0.f};
            #pragma unroll
            for (int kk = 0; kk < 4; ++kk) {
                const short8v bfr = pack8(v[2*kk], v[2*kk+1]);
                acc0 = __builtin_amdgcn_mfma_f32_16x16x32_bf16(a_frag[0][kk], bfr, acc0, 0, 0, 0);
                acc1 = __builtin_amdgcn_mfma_f32_16x16x32_bf16(a_frag[1][kk], bfr, acc1, 0, 0, 0);
            }

            float cminv = 1e30f;
            {
                const float4v x2a = *reinterpret_cast<const float4v*>((const char*)x2s + x2byte);
                #pragma unroll
                for (int r = 0; r < 4; ++r) {
                    const float t = -2.0f * acc0[r];
                    rowmin[0][r] = fminf(rowmin[0][r], yq + t);
                    cminv = fminf(cminv, x2a[r] + t);
                }
            }
            {
                const float4v x2b = *reinterpret_cast<const float4v*>((const char*)x2s + x2byte + 64);
                #pragma unroll
                for (int r = 0; r < 4; ++r) {
                    const float t = -2.0f * acc1[r];
                    rowmin[1][r] = fminf(rowmin[1][r], yq + t);
                    cminv = fminf(cminv, x2b[r] + t);
                }
            }
            // min over the wave's 32 rows; fold y2 so the final combine is min+sum
            cminv = fminf(cminv, __shfl_xor(cminv, 16));
            cminv = fminf(cminv, __shfl_xor(cminv, 32));
            if (lg == tjl) cmin[c] = cminv + yq; // col = c*64 + lane
        }

        __builtin_amdgcn_s_barrier();          // all waves done reading buf c&1
        __builtin_amdgcn_sched_barrier(0);
        if (c < 2) issue_chunk(c + 2);         // refill the buffer just freed
    }

    // ---- per-wave col-mins -> aliased LDS (buffer 0 free after chunk-3 barrier) ----
    #pragma unroll
    for (int s = 0; s < 4; ++s)
        colmin_alias[w * 256 + s * 64 + lane] = cmin[s];

    // ---- loss2: row-mins; add x2[row] at the end ----
    float s2 = 0.f;
    #pragma unroll
    for (int ti = 0; ti < 2; ++ti) {
        const float4v x2v = *reinterpret_cast<const float4v*>((const char*)x2s + x2byte + ti * 64);
        #pragma unroll
        for (int r = 0; r < 4; ++r) {
            float v = rowmin[ti][r];
            v = fminf(v, __shfl_xor(v, 1));
            v = fminf(v, __shfl_xor(v, 2));
            v = fminf(v, __shfl_xor(v, 4));
            v = fminf(v, __shfl_xor(v, 8));
            s2 += x2v[r] + v;
        }
    }
    s2 += __shfl_xor(s2, 16);
    s2 += __shfl_xor(s2, 32);
    if (lane == 0) redA[w] = s2;
    __syncthreads();

    // ---- loss1: min over 8 waves per col (y2 already folded), sum 256 cols ----
    if (tid < 256) {
        float m = colmin_alias[tid];
        #pragma unroll
        for (int ww = 1; ww < 8; ++ww) m = fminf(m, colmin_alias[ww * 256 + tid]);
        #pragma unroll
        for (int s = 1; s < 64; s <<= 1) m += __shfl_xor(m, s);
        if (lane == 0) redB[w] = m;
    }
    __syncthreads();
    if (tid == 0) {
        const float l1 = redB[0] + redB[1] + redB[2] + redB[3];
        float l2 = 0.f;
        #pragma unroll
        for (int ww = 0; ww < 8; ++ww) l2 += redA[ww];
        ch_out[g] = l1 + l2;
    }
}

// Action loss + final reduction -> out[0], out[1]
__global__ __launch_bounds__(256) void final_kernel(
    const float* __restrict__ preds, const float* __restrict__ targ,
    const float* __restrict__ ch, float* __restrict__ out)
{
    __shared__ float rsw[4], rsa[4], rsc[4];
    const int tid = threadIdx.x;
    const int lane = tid & 63, w = tid >> 6;
    float sw = 0.f, sa0 = 0.f, sc = 0.f;
    for (int p = tid; p < NGROUP; p += 256) {
        const float* pp = preds + (size_t)p * T_DIM;
        const float* tt = targ  + (size_t)p * T_DIM;
        float al = 0.f;
        #pragma unroll
        for (int d = 0; d < 4; ++d) { const float df = pp[d] - tt[d]; al += df * df; }
        al *= 0.25f;
        if ((p & 31) == 0) { sw += 10.f * al; sa0 += al; }
        else               { sw += al; }
        sc += ch[p];
    }
    #pragma unroll
    for (int s = 1; s < 64; s <<= 1) {
        sw  += __shfl_xor(sw, s);
        sa0 += __shfl_xor(sa0, s);
        sc  += __shfl_xor(sc, s);
    }
    if (lane == 0) { rsw[w] = sw; rsa[w] = sa0; rsc[w] = sc; }
    __syncthreads();
    if (tid == 0) {
        float tsw = 0.f, tsa = 0.f, tsc = 0.f;
        #pragma unroll
        for (int i = 0; i < 4; ++i) { tsw += rsw[i]; tsa += rsa[i]; tsc += rsc[i]; }
        out[0] = tsw / 2048.f + tsc / 2048.f;
        out[1] = tsa / 64.f;
    }
}

extern "C" void kernel_launch(void* const* d_in, const int* in_sizes, int n_in,
                              void* d_out, int out_size, void* d_ws, size_t ws_size,
                              hipStream_t stream) {
    const float* preds = (const float*)d_in[0];
    const float* targ  = (const float*)d_in[1];
    float* out = (float*)d_out;
    float* ch  = (float*)d_ws; // 2048 floats of per-group chamfer
    chamfer_kernel<<<NGROUP, 512, 0, stream>>>(preds, targ, ch);
    final_kernel<<<1, 256, 0, stream>>>(preds, targ, ch, out);
}

// Round 7
// 143.295 us; speedup vs baseline: 3.3775x; 1.3083x over previous
//
#include <hip/hip_runtime.h>
#include <hip/hip_bf16.h>

#define T_DIM 32772
#define NGROUP 2048

typedef short short8v __attribute__((ext_vector_type(8)));
typedef float float4v __attribute__((ext_vector_type(4)));
typedef unsigned int uint4v __attribute__((ext_vector_type(4)));

// packed f32x2 -> bf16x2 (RTNE) -> u32; compiler emits v_cvt_pk_bf16_f32
__device__ __forceinline__ unsigned int f2bf2(float a, float b) {
    __hip_bfloat162 h = __float22bfloat162_rn(make_float2(a, b));
    union { __hip_bfloat162 h; unsigned int u; } c; c.h = h;
    return c.u;
}

__device__ __forceinline__ short8v pack8(const float4v u0, const float4v u1) {
    uint4v p;
    p[0] = f2bf2(u0[0], u0[1]);
    p[1] = f2bf2(u0[2], u0[3]);
    p[2] = f2bf2(u1[0], u1[1]);
    p[3] = f2bf2(u1[2], u1[3]);
    return __builtin_bit_cast(short8v, p);
}

// Half-group blocks: 4096 blocks of 256 thr (4 waves). Block handles x-rows
// [h*128, h*128+128) of group g and ALL 256 y-rows (staged bf16 in LDS,
// double-buffered, register-prefetched — structure identical to proven R4).
// blockIdx remap puts sibling blocks (same g) on the same XCD for y L2 reuse.
// Outputs: colmin_part[b][256] = min over block's x-rows of (x2-2zz) + y2[col],
//          rowsum[b] = sum over block's x-rows of (x2[row] + min_m(y2-2zz)).
__global__ __launch_bounds__(256) void chamfer_split_kernel(
    const float* __restrict__ preds, const float* __restrict__ targ,
    float* __restrict__ rowsum, float* __restrict__ colmin_part)
{
    __shared__ __align__(16) unsigned short Ys[2][64 * 128]; // 2 x 16 KB bf16
    __shared__ float y2s[256];
    __shared__ float x2s[128];
    __shared__ float redA[4];
    // colmin [4][256] aliased onto Ys[0] (dead after last buf-0 read, chunk 2)
    float* colmin_alias = reinterpret_cast<float*>(&Ys[0][0]);

    const int B = blockIdx.x;
    const int g = ((B >> 4) << 3) | (B & 7); // sibling blocks differ by 8 -> same XCD
    const int h = (B >> 3) & 1;

    const float* gx = targ  + (size_t)g * T_DIM + 4 + (size_t)h * 128 * 128;
    const float* gy = preds + (size_t)g * T_DIM + 4;

    const int tid  = threadIdx.x;
    const int lane = tid & 63;
    const int w    = tid >> 6;   // wave 0..3, owns local x rows [32w, 32w+32)
    const int lg   = lane >> 4;  // k-quarter 0..3
    const int lc   = lane & 15;  // row/col within 16-tile

    // staging: 4 threads per y-row; thread owns 16B bf16-chunks pcb+4j, j=0..3
    const int prow = tid >> 2;   // row within chunk 0..63
    const int pcb  = tid & 3;
    char* Ysb = (char*)Ys;
    int woff[4];
    #pragma unroll
    for (int j = 0; j < 4; ++j) {
        const int cidx = pcb + 4 * j;
        woff[j] = prow * 256 + ((((cidx & 7) + prow) & 7) << 4) + ((cidx & 8) << 4);
    }

    // ---- prefetch y chunk 0 ----
    float4v pf[8];
    {
        const float* src = gy + (size_t)prow * 128 + pcb * 8;
        #pragma unroll
        for (int j = 0; j < 4; ++j) {
            pf[2*j]   = *reinterpret_cast<const float4v*>(src + j * 32);
            pf[2*j+1] = *reinterpret_cast<const float4v*>(src + j * 32 + 4);
        }
    }

    // ---- A fragments + x2 (own-wave rows; registers + LDS) ----
    short8v a_frag[2][4];
    #pragma unroll
    for (int ti = 0; ti < 2; ++ti) {
        const float* xr = gx + (size_t)(w * 32 + ti * 16 + lc) * 128;
        float ss = 0.f;
        #pragma unroll
        for (int kk = 0; kk < 4; ++kk) {
            const float4v u0 = *reinterpret_cast<const float4v*>(xr + kk * 32 + lg * 8);
            const float4v u1 = *reinterpret_cast<const float4v*>(xr + kk * 32 + lg * 8 + 4);
            ss += u0[0]*u0[0] + u0[1]*u0[1] + u0[2]*u0[2] + u0[3]*u0[3];
            ss += u1[0]*u1[0] + u1[1]*u1[1] + u1[2]*u1[2] + u1[3]*u1[3];
            a_frag[ti][kk] = pack8(u0, u1);
        }
        ss += __shfl_xor(ss, 16);
        ss += __shfl_xor(ss, 32);
        if (lg == 0) x2s[w * 32 + ti * 16 + lc] = ss; // read only by own wave
    }

    // ---- write chunk 0 (y2 + add-rotate bf16) ----
    {
        float ss = 0.f;
        #pragma unroll
        for (int q = 0; q < 8; ++q)
            ss += pf[q][0]*pf[q][0] + pf[q][1]*pf[q][1] + pf[q][2]*pf[q][2] + pf[q][3]*pf[q][3];
        ss += __shfl_xor(ss, 1);
        ss += __shfl_xor(ss, 2);
        if (pcb == 0) y2s[prow] = ss;
        #pragma unroll
        for (int j = 0; j < 4; ++j)
            *reinterpret_cast<short8v*>(Ysb + woff[j]) = pack8(pf[2*j], pf[2*j+1]);
    }
    __syncthreads();

    float rowmin[2][4];
    #pragma unroll
    for (int ti = 0; ti < 2; ++ti)
        #pragma unroll
        for (int r = 0; r < 4; ++r) rowmin[ti][r] = 1e30f;
    float cmin[4];

    const int rs0 = ((lg + lc) & 7) << 4;
    const int rs1 = ((lg + lc + 4) & 7) << 4;
    const int x2byte = (w * 32 + lg * 4) * 4; // + ti*64 bytes

    // ---- 4 chunks: reg-prefetch double-buffer (R4-proven) ----
    #pragma unroll
    for (int c = 0; c < 4; ++c) {
        if (c < 3) {
            const float* src = gy + (size_t)((c + 1) * 64 + prow) * 128 + pcb * 8;
            #pragma unroll
            for (int j = 0; j < 4; ++j) {
                pf[2*j]   = *reinterpret_cast<const float4v*>(src + j * 32);
                pf[2*j+1] = *reinterpret_cast<const float4v*>(src + j * 32 + 4);
            }
        }

        char* buf = Ysb + (c & 1) * 16384;
        #pragma unroll
        for (int tjl = 0; tjl < 4; ++tjl) {
            const int tj = c * 4 + tjl;
            const int rbyte = (tjl * 16 + lc) * 256;
            const float y2c = y2s[tj * 16 + lc];

            float4v acc0 = {0.f, 0.f, 0.f, 0.f};
            float4v acc1 = {0.f, 0.f, 0.f, 0.f};
            {
                short8v b0 = *reinterpret_cast<const short8v*>(buf + rbyte + rs0);
                short8v b1 = *reinterpret_cast<const short8v*>(buf + rbyte + rs1);
                acc0 = __builtin_amdgcn_mfma_f32_16x16x32_bf16(a_frag[0][0], b0, acc0, 0, 0, 0);
                acc1 = __builtin_amdgcn_mfma_f32_16x16x32_bf16(a_frag[1][0], b0, acc1, 0, 0, 0);
                acc0 = __builtin_amdgcn_mfma_f32_16x16x32_bf16(a_frag[0][1], b1, acc0, 0, 0, 0);
                acc1 = __builtin_amdgcn_mfma_f32_16x16x32_bf16(a_frag[1][1], b1, acc1, 0, 0, 0);
                b0 = *reinterpret_cast<const short8v*>(buf + rbyte + 128 + rs0);
                b1 = *reinterpret_cast<const short8v*>(buf + rbyte + 128 + rs1);
                acc0 = __builtin_amdgcn_mfma_f32_16x16x32_bf16(a_frag[0][2], b0, acc0, 0, 0, 0);
                acc1 = __builtin_amdgcn_mfma_f32_16x16x32_bf16(a_frag[1][2], b0, acc1, 0, 0, 0);
                acc0 = __builtin_amdgcn_mfma_f32_16x16x32_bf16(a_frag[0][3], b1, acc0, 0, 0, 0);
                acc1 = __builtin_amdgcn_mfma_f32_16x16x32_bf16(a_frag[1][3], b1, acc1, 0, 0, 0);
            }

            float cminv = 1e30f;
            {
                const float4v x2a = *reinterpret_cast<const float4v*>((const char*)x2s + x2byte);
                #pragma unroll
                for (int r = 0; r < 4; ++r) {
                    const float t = -2.0f * acc0[r];
                    rowmin[0][r] = fminf(rowmin[0][r], y2c + t);
                    cminv = fminf(cminv, x2a[r] + t);
                }
            }
            {
                const float4v x2b = *reinterpret_cast<const float4v*>((const char*)x2s + x2byte + 64);
                #pragma unroll
                for (int r = 0; r < 4; ++r) {
                    const float t = -2.0f * acc1[r];
                    rowmin[1][r] = fminf(rowmin[1][r], y2c + t);
                    cminv = fminf(cminv, x2b[r] + t);
                }
            }
            // min over the wave's 32 local rows; fold y2 (col-constant) here
            cminv = fminf(cminv, __shfl_xor(cminv, 16));
            cminv = fminf(cminv, __shfl_xor(cminv, 32));
            if (lg == tjl) cmin[c] = cminv + y2c; // col = c*64 + lane
        }

        if (c < 3) {
            float ss = 0.f;
            #pragma unroll
            for (int q = 0; q < 8; ++q)
                ss += pf[q][0]*pf[q][0] + pf[q][1]*pf[q][1] + pf[q][2]*pf[q][2] + pf[q][3]*pf[q][3];
            ss += __shfl_xor(ss, 1);
            ss += __shfl_xor(ss, 2);
            if (pcb == 0) y2s[(c + 1) * 64 + prow] = ss;
            char* wbuf = Ysb + ((c + 1) & 1) * 16384;
            #pragma unroll
            for (int j = 0; j < 4; ++j)
                *reinterpret_cast<short8v*>(wbuf + woff[j]) = pack8(pf[2*j], pf[2*j+1]);
            __syncthreads();
        }
    }

    // ---- per-wave col-mins -> aliased LDS (buf 0 dead after last barrier) ----
    #pragma unroll
    for (int s = 0; s < 4; ++s)
        colmin_alias[w * 256 + s * 64 + lane] = cmin[s];

    // ---- loss2 partial: row-mins; add x2[row]; one float per block ----
    float s2 = 0.f;
    #pragma unroll
    for (int ti = 0; ti < 2; ++ti) {
        const float4v x2v = *reinterpret_cast<const float4v*>((const char*)x2s + x2byte + ti * 64);
        #pragma unroll
        for (int r = 0; r < 4; ++r) {
            float v = rowmin[ti][r];
            v = fminf(v, __shfl_xor(v, 1));
            v = fminf(v, __shfl_xor(v, 2));
            v = fminf(v, __shfl_xor(v, 4));
            v = fminf(v, __shfl_xor(v, 8));
            s2 += x2v[r] + v;
        }
    }
    s2 += __shfl_xor(s2, 16);
    s2 += __shfl_xor(s2, 32);
    if (lane == 0) redA[w] = s2;
    __syncthreads();

    // ---- emit partials ----
    if (tid < 256) {
        float m = colmin_alias[tid];
        #pragma unroll
        for (int ww = 1; ww < 4; ++ww) m = fminf(m, colmin_alias[ww * 256 + tid]);
        colmin_part[(size_t)B * 256 + tid] = m;
    }
    if (tid == 0)
        rowsum[B] = redA[0] + redA[1] + redA[2] + redA[3];
}

// Combine the two half-group blocks -> per-group chamfer
__global__ __launch_bounds__(256) void group_reduce_kernel(
    const float* __restrict__ rowsum, const float* __restrict__ colmin_part,
    float* __restrict__ ch)
{
    __shared__ float red[4];
    const int gq = blockIdx.x;             // group
    const int tid = threadIdx.x;
    const int lane = tid & 63, w = tid >> 6;
    // sibling blocks of group g: B with ((B>>4)<<3)|(B&7) == g, h = (B>>3)&1
    const int B0 = ((gq >> 3) << 4) | (gq & 7);
    const int B1 = B0 | 8;
    float m = fminf(colmin_part[(size_t)B0 * 256 + tid],
                    colmin_part[(size_t)B1 * 256 + tid]);
    #pragma unroll
    for (int s = 1; s < 64; s <<= 1) m += __shfl_xor(m, s);
    if (lane == 0) red[w] = m;
    __syncthreads();
    if (tid == 0)
        ch[gq] = red[0] + red[1] + red[2] + red[3] + rowsum[B0] + rowsum[B1];
}

// Action loss + final reduction -> out[0], out[1]
__global__ __launch_bounds__(256) void final_kernel(
    const float* __restrict__ preds, const float* __restrict__ targ,
    const float* __restrict__ ch, float* __restrict__ out)
{
    __shared__ float rsw[4], rsa[4], rsc[4];
    const int tid = threadIdx.x;
    const int lane = tid & 63, w = tid >> 6;
    float sw = 0.f, sa0 = 0.f, sc = 0.f;
    for (int p = tid; p < NGROUP; p += 256) {
        const float* pp = preds + (size_t)p * T_DIM;
        const float* tt = targ  + (size_t)p * T_DIM;
        float al = 0.f;
        #pragma unroll
        for (int d = 0; d < 4; ++d) { const float df = pp[d] - tt[d]; al += df * df; }
        al *= 0.25f;
        if ((p & 31) == 0) { sw += 10.f * al; sa0 += al; }
        else               { sw += al; }
        sc += ch[p];
    }
    #pragma unroll
    for (int s = 1; s < 64; s <<= 1) {
        sw  += __shfl_xor(sw, s);
        sa0 += __shfl_xor(sa0, s);
        sc  += __shfl_xor(sc, s);
    }
    if (lane == 0) { rsw[w] = sw; rsa[w] = sa0; rsc[w] = sc; }
    __syncthreads();
    if (tid == 0) {
        float tsw = 0.f, tsa = 0.f, tsc = 0.f;
        #pragma unroll
        for (int i = 0; i < 4; ++i) { tsw += rsw[i]; tsa += rsa[i]; tsc += rsc[i]; }
        out[0] = tsw / 2048.f + tsc / 2048.f;
        out[1] = tsa / 64.f;
    }
}

extern "C" void kernel_launch(void* const* d_in, const int* in_sizes, int n_in,
                              void* d_out, int out_size, void* d_ws, size_t ws_size,
                              hipStream_t stream) {
    const float* preds = (const float*)d_in[0];
    const float* targ  = (const float*)d_in[1];
    float* out = (float*)d_out;
    float* ws  = (float*)d_ws;
    // ws layout (floats): ch[2048] | rowsum[4096] | pad | colmin_part[4096*256]
    float* ch      = ws;
    float* rowsum  = ws + 2048;
    float* colmin  = ws + 8192;
    chamfer_split_kernel<<<2 * NGROUP, 256, 0, stream>>>(preds, targ, rowsum, colmin);
    group_reduce_kernel<<<NGROUP, 256, 0, stream>>>(rowsum, colmin, ch);
    final_kernel<<<1, 256, 0, stream>>>(preds, targ, ch, out);
}

// Round 8
// 128.532 us; speedup vs baseline: 3.7654x; 1.1149x over previous
//
#include <hip/hip_runtime.h>
#include <hip/hip_bf16.h>

#define T_DIM 32772
#define NGROUP 2048

typedef short short8v __attribute__((ext_vector_type(8)));
typedef float float4v __attribute__((ext_vector_type(4)));
typedef unsigned int uint4v __attribute__((ext_vector_type(4)));

// packed f32x2 -> bf16x2 (RTNE) -> u32; compiler emits v_cvt_pk_bf16_f32
__device__ __forceinline__ unsigned int f2bf2(float a, float b) {
    __hip_bfloat162 h = __float22bfloat162_rn(make_float2(a, b));
    union { __hip_bfloat162 h; unsigned int u; } c; c.h = h;
    return c.u;
}

__device__ __forceinline__ short8v pack8(const float4v u0, const float4v u1) {
    uint4v p;
    p[0] = f2bf2(u0[0], u0[1]);
    p[1] = f2bf2(u0[2], u0[3]);
    p[2] = f2bf2(u1[0], u1[1]);
    p[3] = f2bf2(u1[2], u1[3]);
    return __builtin_bit_cast(short8v, p);
}

// One block per chamfer group g (B*H=2048), 8 waves.
// x = targ obs (n, 256x128): per-wave register A-frags (wave w owns rows 32w..32w+31).
// y = preds obs (m, 256x128): staged ONCE, whole, as bf16 in 64KB LDS (add-rotate
//     layout: 16B chunk c of row r at r*256 + (((c&7)+r)&7)*16 + ((c&8)<<4)).
// Sweep of 16 col-tiles is BARRIER-FREE: waves drift, pipes overlap.
// P = x2[n] + y2[m] - 2*x.y ; loss1 = sum_m min_n P ; loss2 = sum_n min_m P
__global__ __launch_bounds__(512) void chamfer_kernel(
    const float* __restrict__ preds, const float* __restrict__ targ,
    float* __restrict__ ch_out)
{
    __shared__ __align__(16) unsigned short Ys[256 * 128]; // 64 KB bf16, whole y
    __shared__ float y2s[256];
    __shared__ float x2s[256];
    __shared__ float redA[8];
    __shared__ float redB[4];
    // colmin [8][256] aliased onto Ys (dead after the post-sweep barrier)
    float* colmin_alias = reinterpret_cast<float*>(&Ys[0]);

    const int g = blockIdx.x;
    const float* gx = targ  + (size_t)g * T_DIM + 4;
    const float* gy = preds + (size_t)g * T_DIM + 4;

    const int tid  = threadIdx.x;
    const int lane = tid & 63;
    const int w    = tid >> 6;   // wave 0..7, owns x rows [32w, 32w+32)
    const int lg   = lane >> 4;  // k-quarter 0..3
    const int lc   = lane & 15;  // row/col within 16-tile

    char* Ysb = (char*)Ys;

    // ---- A fragments to registers + x2 to LDS (own-wave rows) ----
    short8v a_frag[2][4];
    #pragma unroll
    for (int ti = 0; ti < 2; ++ti) {
        const float* xr = gx + (size_t)(w * 32 + ti * 16 + lc) * 128;
        float ss = 0.f;
        #pragma unroll
        for (int kk = 0; kk < 4; ++kk) {
            const float4v u0 = *reinterpret_cast<const float4v*>(xr + kk * 32 + lg * 8);
            const float4v u1 = *reinterpret_cast<const float4v*>(xr + kk * 32 + lg * 8 + 4);
            ss += u0[0]*u0[0] + u0[1]*u0[1] + u0[2]*u0[2] + u0[3]*u0[3];
            ss += u1[0]*u1[0] + u1[1]*u1[1] + u1[2]*u1[2] + u1[3]*u1[3];
            a_frag[ti][kk] = pack8(u0, u1);
        }
        ss += __shfl_xor(ss, 16);
        ss += __shfl_xor(ss, 32);
        if (lg == 0) x2s[w * 32 + ti * 16 + lc] = ss; // read only by own wave
    }

    // ---- stage whole y: 2 threads/row, 4 batches of 16 f32 (16 live regs) ----
    {
        const int prow = tid >> 1;  // row 0..255
        const int h2   = tid & 1;   // half-row
        const float* src = gy + (size_t)prow * 128 + h2 * 64;
        float ss = 0.f;
        #pragma unroll
        for (int j = 0; j < 4; ++j) {
            const float4v u0 = *reinterpret_cast<const float4v*>(src + j * 16);
            const float4v u1 = *reinterpret_cast<const float4v*>(src + j * 16 + 4);
            const float4v u2 = *reinterpret_cast<const float4v*>(src + j * 16 + 8);
            const float4v u3 = *reinterpret_cast<const float4v*>(src + j * 16 + 12);
            ss += u0[0]*u0[0] + u0[1]*u0[1] + u0[2]*u0[2] + u0[3]*u0[3];
            ss += u1[0]*u1[0] + u1[1]*u1[1] + u1[2]*u1[2] + u1[3]*u1[3];
            ss += u2[0]*u2[0] + u2[1]*u2[1] + u2[2]*u2[2] + u2[3]*u2[3];
            ss += u3[0]*u3[0] + u3[1]*u3[1] + u3[2]*u3[2] + u3[3]*u3[3];
            const int c0 = h2 * 8 + 2 * j;
            const int c1 = c0 + 1;
            const int o0 = prow * 256 + ((((c0 & 7) + prow) & 7) << 4) + ((c0 & 8) << 4);
            const int o1 = prow * 256 + ((((c1 & 7) + prow) & 7) << 4) + ((c1 & 8) << 4);
            *reinterpret_cast<short8v*>(Ysb + o0) = pack8(u0, u1);
            *reinterpret_cast<short8v*>(Ysb + o1) = pack8(u2, u3);
        }
        ss += __shfl_xor(ss, 1);
        if (h2 == 0) y2s[prow] = ss;
    }
    __syncthreads(); // staging complete — the ONLY pre-sweep barrier

    float rowmin[2][4];
    #pragma unroll
    for (int ti = 0; ti < 2; ++ti)
        #pragma unroll
        for (int r = 0; r < 4; ++r) rowmin[ti][r] = 1e30f;
    float cmin[4];

    // read slots (conflict-free add-rotate; b_frag[kk] = chunk 4kk+lg of row)
    const int rs0 = ((lg + lc) & 7) << 4;
    const int rs1 = ((lg + lc + 4) & 7) << 4;
    const int x2byte = (w * 32 + lg * 4) * 4; // + ti*64 bytes

    // ---- 16 col-tiles, barrier-free sweep ----
    #pragma unroll
    for (int tj = 0; tj < 16; ++tj) {
        const int rbyte = (tj * 16 + lc) * 256;
        const float y2c = y2s[tj * 16 + lc];

        float4v acc0 = {0.f, 0.f, 0.f, 0.f};
        float4v acc1 = {0.f, 0.f, 0.f, 0.f};
        {
            short8v b0 = *reinterpret_cast<const short8v*>(Ysb + rbyte + rs0);
            short8v b1 = *reinterpret_cast<const short8v*>(Ysb + rbyte + rs1);
            acc0 = __builtin_amdgcn_mfma_f32_16x16x32_bf16(a_frag[0][0], b0, acc0, 0, 0, 0);
            acc1 = __builtin_amdgcn_mfma_f32_16x16x32_bf16(a_frag[1][0], b0, acc1, 0, 0, 0);
            acc0 = __builtin_amdgcn_mfma_f32_16x16x32_bf16(a_frag[0][1], b1, acc0, 0, 0, 0);
            acc1 = __builtin_amdgcn_mfma_f32_16x16x32_bf16(a_frag[1][1], b1, acc1, 0, 0, 0);
            b0 = *reinterpret_cast<const short8v*>(Ysb + rbyte + 128 + rs0);
            b1 = *reinterpret_cast<const short8v*>(Ysb + rbyte + 128 + rs1);
            acc0 = __builtin_amdgcn_mfma_f32_16x16x32_bf16(a_frag[0][2], b0, acc0, 0, 0, 0);
            acc1 = __builtin_amdgcn_mfma_f32_16x16x32_bf16(a_frag[1][2], b0, acc1, 0, 0, 0);
            acc0 = __builtin_amdgcn_mfma_f32_16x16x32_bf16(a_frag[0][3], b1, acc0, 0, 0, 0);
            acc1 = __builtin_amdgcn_mfma_f32_16x16x32_bf16(a_frag[1][3], b1, acc1, 0, 0, 0);
        }

        float cminv = 1e30f;
        {
            const float4v x2a = *reinterpret_cast<const float4v*>((const char*)x2s + x2byte);
            #pragma unroll
            for (int r = 0; r < 4; ++r) {
                const float t = -2.0f * acc0[r];
                rowmin[0][r] = fminf(rowmin[0][r], y2c + t);
                cminv = fminf(cminv, x2a[r] + t);
            }
        }
        {
            const float4v x2b = *reinterpret_cast<const float4v*>((const char*)x2s + x2byte + 64);
            #pragma unroll
            for (int r = 0; r < 4; ++r) {
                const float t = -2.0f * acc1[r];
                rowmin[1][r] = fminf(rowmin[1][r], y2c + t);
                cminv = fminf(cminv, x2b[r] + t);
            }
        }
        // min over the wave's 32 rows; fold y2 (col-constant) here
        cminv = fminf(cminv, __shfl_xor(cminv, 16));
        cminv = fminf(cminv, __shfl_xor(cminv, 32));
        if (lg == (tj & 3)) cmin[tj >> 2] = cminv + y2c; // col = (tj>>2)*64 + lane
    }

    __syncthreads(); // all waves done reading Ys — alias becomes safe

    // ---- per-wave col-mins -> aliased LDS ----
    #pragma unroll
    for (int s = 0; s < 4; ++s)
        colmin_alias[w * 256 + s * 64 + lane] = cmin[s];

    // ---- loss2: row-mins; add x2[row] at the end ----
    float s2 = 0.f;
    #pragma unroll
    for (int ti = 0; ti < 2; ++ti) {
        const float4v x2v = *reinterpret_cast<const float4v*>((const char*)x2s + x2byte + ti * 64);
        #pragma unroll
        for (int r = 0; r < 4; ++r) {
            float v = rowmin[ti][r];
            v = fminf(v, __shfl_xor(v, 1));
            v = fminf(v, __shfl_xor(v, 2));
            v = fminf(v, __shfl_xor(v, 4));
            v = fminf(v, __shfl_xor(v, 8));
            s2 += x2v[r] + v;
        }
    }
    s2 += __shfl_xor(s2, 16);
    s2 += __shfl_xor(s2, 32);
    if (lane == 0) redA[w] = s2;
    __syncthreads();

    // ---- loss1: min over 8 waves per col (y2 folded), sum over 256 cols ----
    if (tid < 256) {
        float m = colmin_alias[tid];
        #pragma unroll
        for (int ww = 1; ww < 8; ++ww) m = fminf(m, colmin_alias[ww * 256 + tid]);
        #pragma unroll
        for (int s = 1; s < 64; s <<= 1) m += __shfl_xor(m, s);
        if (lane == 0) redB[w] = m;
    }
    __syncthreads();
    if (tid == 0) {
        const float l1 = redB[0] + redB[1] + redB[2] + redB[3];
        float l2 = 0.f;
        #pragma unroll
        for (int ww = 0; ww < 8; ++ww) l2 += redA[ww];
        ch_out[g] = l1 + l2;
    }
}

// Action loss + final reduction -> out[0], out[1]
__global__ __launch_bounds__(256) void final_kernel(
    const float* __restrict__ preds, const float* __restrict__ targ,
    const float* __restrict__ ch, float* __restrict__ out)
{
    __shared__ float rsw[4], rsa[4], rsc[4];
    const int tid = threadIdx.x;
    const int lane = tid & 63, w = tid >> 6;
    float sw = 0.f, sa0 = 0.f, sc = 0.f;
    for (int p = tid; p < NGROUP; p += 256) {
        const float* pp = preds + (size_t)p * T_DIM;
        const float* tt = targ  + (size_t)p * T_DIM;
        float al = 0.f;
        #pragma unroll
        for (int d = 0; d < 4; ++d) { const float df = pp[d] - tt[d]; al += df * df; }
        al *= 0.25f;
        if ((p & 31) == 0) { sw += 10.f * al; sa0 += al; }
        else               { sw += al; }
        sc += ch[p];
    }
    #pragma unroll
    for (int s = 1; s < 64; s <<= 1) {
        sw  += __shfl_xor(sw, s);
        sa0 += __shfl_xor(sa0, s);
        sc  += __shfl_xor(sc, s);
    }
    if (lane == 0) { rsw[w] = sw; rsa[w] = sa0; rsc[w] = sc; }
    __syncthreads();
    if (tid == 0) {
        float tsw = 0.f, tsa = 0.f, tsc = 0.f;
        #pragma unroll
        for (int i = 0; i < 4; ++i) { tsw += rsw[i]; tsa += rsa[i]; tsc += rsc[i]; }
        out[0] = tsw / 2048.f + tsc / 2048.f;
        out[1] = tsa / 64.f;
    }
}

extern "C" void kernel_launch(void* const* d_in, const int* in_sizes, int n_in,
                              void* d_out, int out_size, void* d_ws, size_t ws_size,
                              hipStream_t stream) {
    const float* preds = (const float*)d_in[0];
    const float* targ  = (const float*)d_in[1];
    float* out = (float*)d_out;
    float* ch  = (float*)d_ws; // 2048 floats of per-group chamfer
    chamfer_kernel<<<NGROUP, 512, 0, stream>>>(preds, targ, ch);
    final_kernel<<<1, 256, 0, stream>>>(preds, targ, ch, out);
}

// Round 9
// 119.559 us; speedup vs baseline: 4.0481x; 1.0751x over previous
//
#include <hip/hip_runtime.h>
#include <hip/hip_bf16.h>

#define T_DIM 32772
#define NGROUP 2048

typedef short short8v __attribute__((ext_vector_type(8)));
typedef float float4v __attribute__((ext_vector_type(4)));
typedef unsigned int uint4v __attribute__((ext_vector_type(4)));

// packed f32x2 -> bf16x2 (RTNE) -> u32; compiler emits v_cvt_pk_bf16_f32
__device__ __forceinline__ unsigned int f2bf2(float a, float b) {
    __hip_bfloat162 h = __float22bfloat162_rn(make_float2(a, b));
    union { __hip_bfloat162 h; unsigned int u; } c; c.h = h;
    return c.u;
}

__device__ __forceinline__ short8v pack8(const float4v u0, const float4v u1) {
    uint4v p;
    p[0] = f2bf2(u0[0], u0[1]);
    p[1] = f2bf2(u0[2], u0[3]);
    p[2] = f2bf2(u1[0], u1[1]);
    p[3] = f2bf2(u1[2], u1[3]);
    return __builtin_bit_cast(short8v, p);
}

// One block per chamfer group g (B*H=2048), 8 waves, ~34.4 KB LDS -> 4 blocks/CU.
// x = targ obs (n, 256x128): per-wave register A-frags (wave w owns rows 32w..32w+31).
// y = preds obs (m, 256x128): staged in 2 halves of 128 rows (32 KB bf16, add-rotate
//     layout: 16B chunk c of row r at r*256 + (((c&7)+r)&7)*16 + ((c&8)<<4)).
// Each half's 8-col-tile sweep is barrier-free; 4 blocks/CU stagger so staging
// of one block hides under sweeps of the others.
// P = x2[n] + y2[m] - 2*x.y ; loss1 = sum_m min_n P ; loss2 = sum_n min_m P
__global__ __launch_bounds__(512) void chamfer_kernel(
    const float* __restrict__ preds, const float* __restrict__ targ,
    float* __restrict__ ch_out)
{
    __shared__ __align__(16) unsigned short Ys[128 * 128]; // 32 KB bf16 (half of y)
    __shared__ float y2s[128];
    __shared__ float x2s[256];
    __shared__ float redA[8];
    __shared__ float redB[4];
    // colmin [8][256] aliased onto Ys (dead after the final sweep barrier)
    float* colmin_alias = reinterpret_cast<float*>(&Ys[0]);

    const int g = blockIdx.x;
    const float* gx = targ  + (size_t)g * T_DIM + 4;
    const float* gy = preds + (size_t)g * T_DIM + 4;

    const int tid  = threadIdx.x;
    const int lane = tid & 63;
    const int w    = tid >> 6;   // wave 0..7, owns x rows [32w, 32w+32)
    const int lg   = lane >> 4;  // k-quarter 0..3
    const int lc   = lane & 15;  // row/col within 16-tile

    char* Ysb = (char*)Ys;

    // staging decomposition: 4 threads per row (128 rows), thread owns 32 floats
    const int prow = tid >> 2;   // row within half 0..127
    const int q    = tid & 3;    // quarter of the row

    // ---- A fragments to registers + x2 to LDS (own-wave rows) ----
    short8v a_frag[2][4];
    #pragma unroll
    for (int ti = 0; ti < 2; ++ti) {
        const float* xr = gx + (size_t)(w * 32 + ti * 16 + lc) * 128;
        float ss = 0.f;
        #pragma unroll
        for (int kk = 0; kk < 4; ++kk) {
            const float4v u0 = *reinterpret_cast<const float4v*>(xr + kk * 32 + lg * 8);
            const float4v u1 = *reinterpret_cast<const float4v*>(xr + kk * 32 + lg * 8 + 4);
            ss += u0[0]*u0[0] + u0[1]*u0[1] + u0[2]*u0[2] + u0[3]*u0[3];
            ss += u1[0]*u1[0] + u1[1]*u1[1] + u1[2]*u1[2] + u1[3]*u1[3];
            a_frag[ti][kk] = pack8(u0, u1);
        }
        ss += __shfl_xor(ss, 16);
        ss += __shfl_xor(ss, 32);
        if (lg == 0) x2s[w * 32 + ti * 16 + lc] = ss; // read only by own wave
    }

    float rowmin[2][4];
    #pragma unroll
    for (int ti = 0; ti < 2; ++ti)
        #pragma unroll
        for (int r = 0; r < 4; ++r) rowmin[ti][r] = 1e30f;
    float cmin[4];

    // read slots (conflict-free add-rotate; b_frag[kk] = chunk 4kk+lg of row)
    const int rs0 = ((lg + lc) & 7) << 4;
    const int rs1 = ((lg + lc + 4) & 7) << 4;
    const int x2byte = (w * 32 + lg * 4) * 4; // + ti*64 bytes

    // ---- two halves: stage 128 y-rows -> barrier -> barrier-free 8-tile sweep ----
    #pragma unroll
    for (int h = 0; h < 2; ++h) {
        // stage half h (register-light: 2 sequential batches of 4 x float4)
        {
            const float* src = gy + (size_t)(h * 128 + prow) * 128 + q * 32;
            float ss = 0.f;
            #pragma unroll
            for (int j = 0; j < 2; ++j) {
                const float4v u0 = *reinterpret_cast<const float4v*>(src + j * 16);
                const float4v u1 = *reinterpret_cast<const float4v*>(src + j * 16 + 4);
                const float4v u2 = *reinterpret_cast<const float4v*>(src + j * 16 + 8);
                const float4v u3 = *reinterpret_cast<const float4v*>(src + j * 16 + 12);
                ss += u0[0]*u0[0] + u0[1]*u0[1] + u0[2]*u0[2] + u0[3]*u0[3];
                ss += u1[0]*u1[0] + u1[1]*u1[1] + u1[2]*u1[2] + u1[3]*u1[3];
                ss += u2[0]*u2[0] + u2[1]*u2[1] + u2[2]*u2[2] + u2[3]*u2[3];
                ss += u3[0]*u3[0] + u3[1]*u3[1] + u3[2]*u3[2] + u3[3]*u3[3];
                const int c0 = q * 4 + 2 * j;
                const int c1 = c0 + 1;
                const int o0 = prow * 256 + ((((c0 & 7) + prow) & 7) << 4) + ((c0 & 8) << 4);
                const int o1 = prow * 256 + ((((c1 & 7) + prow) & 7) << 4) + ((c1 & 8) << 4);
                *reinterpret_cast<short8v*>(Ysb + o0) = pack8(u0, u1);
                *reinterpret_cast<short8v*>(Ysb + o1) = pack8(u2, u3);
            }
            ss += __shfl_xor(ss, 1);
            ss += __shfl_xor(ss, 2);
            if (q == 0) y2s[prow] = ss;
        }
        __syncthreads(); // half h staged

        // barrier-free sweep over this half's 8 col-tiles
        #pragma unroll
        for (int tjl = 0; tjl < 8; ++tjl) {
            const int rbyte = (tjl * 16 + lc) * 256;
            const float y2c = y2s[tjl * 16 + lc];

            float4v acc0 = {0.f, 0.f, 0.f, 0.f};
            float4v acc1 = {0.f, 0.f, 0.f, 0.f};
            {
                short8v b0 = *reinterpret_cast<const short8v*>(Ysb + rbyte + rs0);
                short8v b1 = *reinterpret_cast<const short8v*>(Ysb + rbyte + rs1);
                acc0 = __builtin_amdgcn_mfma_f32_16x16x32_bf16(a_frag[0][0], b0, acc0, 0, 0, 0);
                acc1 = __builtin_amdgcn_mfma_f32_16x16x32_bf16(a_frag[1][0], b0, acc1, 0, 0, 0);
                acc0 = __builtin_amdgcn_mfma_f32_16x16x32_bf16(a_frag[0][1], b1, acc0, 0, 0, 0);
                acc1 = __builtin_amdgcn_mfma_f32_16x16x32_bf16(a_frag[1][1], b1, acc1, 0, 0, 0);
                b0 = *reinterpret_cast<const short8v*>(Ysb + rbyte + 128 + rs0);
                b1 = *reinterpret_cast<const short8v*>(Ysb + rbyte + 128 + rs1);
                acc0 = __builtin_amdgcn_mfma_f32_16x16x32_bf16(a_frag[0][2], b0, acc0, 0, 0, 0);
                acc1 = __builtin_amdgcn_mfma_f32_16x16x32_bf16(a_frag[1][2], b0, acc1, 0, 0, 0);
                acc0 = __builtin_amdgcn_mfma_f32_16x16x32_bf16(a_frag[0][3], b1, acc0, 0, 0, 0);
                acc1 = __builtin_amdgcn_mfma_f32_16x16x32_bf16(a_frag[1][3], b1, acc1, 0, 0, 0);
            }

            float cminv = 1e30f;
            {
                const float4v x2a = *reinterpret_cast<const float4v*>((const char*)x2s + x2byte);
                #pragma unroll
                for (int r = 0; r < 4; ++r) {
                    const float t = -2.0f * acc0[r];
                    rowmin[0][r] = fminf(rowmin[0][r], y2c + t);
                    cminv = fminf(cminv, x2a[r] + t);
                }
            }
            {
                const float4v x2b = *reinterpret_cast<const float4v*>((const char*)x2s + x2byte + 64);
                #pragma unroll
                for (int r = 0; r < 4; ++r) {
                    const float t = -2.0f * acc1[r];
                    rowmin[1][r] = fminf(rowmin[1][r], y2c + t);
                    cminv = fminf(cminv, x2b[r] + t);
                }
            }
            // min over the wave's 32 rows; fold y2 (col-constant) here
            cminv = fminf(cminv, __shfl_xor(cminv, 16));
            cminv = fminf(cminv, __shfl_xor(cminv, 32));
            // col = h*128 + (tjl>>2)*64 + lane
            if (lg == (tjl & 3)) cmin[h * 2 + (tjl >> 2)] = cminv + y2c;
        }

        __syncthreads(); // all waves done reading Ys/y2s before re-stage / alias
    }

    // ---- per-wave col-mins -> aliased LDS (Ys dead now) ----
    #pragma unroll
    for (int s = 0; s < 4; ++s)
        colmin_alias[w * 256 + s * 64 + lane] = cmin[s];

    // ---- loss2: row-mins; add x2[row] at the end ----
    float s2 = 0.f;
    #pragma unroll
    for (int ti = 0; ti < 2; ++ti) {
        const float4v x2v = *reinterpret_cast<const float4v*>((const char*)x2s + x2byte + ti * 64);
        #pragma unroll
        for (int r = 0; r < 4; ++r) {
            float v = rowmin[ti][r];
            v = fminf(v, __shfl_xor(v, 1));
            v = fminf(v, __shfl_xor(v, 2));
            v = fminf(v, __shfl_xor(v, 4));
            v = fminf(v, __shfl_xor(v, 8));
            s2 += x2v[r] + v;
        }
    }
    s2 += __shfl_xor(s2, 16);
    s2 += __shfl_xor(s2, 32);
    if (lane == 0) redA[w] = s2;
    __syncthreads();

    // ---- loss1: min over 8 waves per col (y2 folded), sum over 256 cols ----
    if (tid < 256) {
        float m = colmin_alias[tid];
        #pragma unroll
        for (int ww = 1; ww < 8; ++ww) m = fminf(m, colmin_alias[ww * 256 + tid]);
        #pragma unroll
        for (int s = 1; s < 64; s <<= 1) m += __shfl_xor(m, s);
        if (lane == 0) redB[w] = m;
    }
    __syncthreads();
    if (tid == 0) {
        const float l1 = redB[0] + redB[1] + redB[2] + redB[3];
        float l2 = 0.f;
        #pragma unroll
        for (int ww = 0; ww < 8; ++ww) l2 += redA[ww];
        ch_out[g] = l1 + l2;
    }
}

// Action loss + final reduction -> out[0], out[1]
__global__ __launch_bounds__(256) void final_kernel(
    const float* __restrict__ preds, const float* __restrict__ targ,
    const float* __restrict__ ch, float* __restrict__ out)
{
    __shared__ float rsw[4], rsa[4], rsc[4];
    const int tid = threadIdx.x;
    const int lane = tid & 63, w = tid >> 6;
    float sw = 0.f, sa0 = 0.f, sc = 0.f;
    for (int p = tid; p < NGROUP; p += 256) {
        const float* pp = preds + (size_t)p * T_DIM;
        const float* tt = targ  + (size_t)p * T_DIM;
        float al = 0.f;
        #pragma unroll
        for (int d = 0; d < 4; ++d) { const float df = pp[d] - tt[d]; al += df * df; }
        al *= 0.25f;
        if ((p & 31) == 0) { sw += 10.f * al; sa0 += al; }
        else               { sw += al; }
        sc += ch[p];
    }
    #pragma unroll
    for (int s = 1; s < 64; s <<= 1) {
        sw  += __shfl_xor(sw, s);
        sa0 += __shfl_xor(sa0, s);
        sc  += __shfl_xor(sc, s);
    }
    if (lane == 0) { rsw[w] = sw; rsa[w] = sa0; rsc[w] = sc; }
    __syncthreads();
    if (tid == 0) {
        float tsw = 0.f, tsa = 0.f, tsc = 0.f;
        #pragma unroll
        for (int i = 0; i < 4; ++i) { tsw += rsw[i]; tsa += rsa[i]; tsc += rsc[i]; }
        out[0] = tsw / 2048.f + tsc / 2048.f;
        out[1] = tsa / 64.f;
    }
}

extern "C" void kernel_launch(void* const* d_in, const int* in_sizes, int n_in,
                              void* d_out, int out_size, void* d_ws, size_t ws_size,
                              hipStream_t stream) {
    const float* preds = (const float*)d_in[0];
    const float* targ  = (const float*)d_in[1];
    float* out = (float*)d_out;
    float* ch  = (float*)d_ws; // 2048 floats of per-group chamfer
    chamfer_kernel<<<NGROUP, 512, 0, stream>>>(preds, targ, ch);
    final_kernel<<<1, 256, 0, stream>>>(preds, targ, ch, out);
}